// Round 4
// baseline (1193.072 us; speedup 1.0000x reference)
//
#include <hip/hip_runtime.h>

#define NCLS 8
#define NPT  2048
#define DIM  64
#define FINF 3.402823466e38f
#define INFK 0xFFFFFFFFu
#define INF64 0xFFFFFFFFFFFFFFFFull

typedef unsigned int u32;
typedef unsigned long long u64;
typedef unsigned short u16;
typedef __bf16 bf16_t;
typedef __attribute__((ext_vector_type(8))) bf16_t bf16x8;
typedef __attribute__((ext_vector_type(4))) float f32x4;
typedef __attribute__((ext_vector_type(4))) u32 u32x4;

#define MFMA16(a, b, c) __builtin_amdgcn_mfma_f32_16x16x32_bf16((a), (b), (c), 0, 0, 0)

// ---------------------------------------------------------------------------
// Kernel 1: fp32 -> bf16 hi/lo split (x = hi + lo) + exact fp32 row norms.
// One wave per row (DIM == 64).
// ---------------------------------------------------------------------------
__global__ void conv_norms_kernel(const float* __restrict__ x, u16* __restrict__ hi,
                                  u16* __restrict__ lo, float* __restrict__ sq) {
    int row  = blockIdx.x * 4 + (threadIdx.x >> 6);
    int lane = threadIdx.x & 63;
    size_t idx = (size_t)row * DIM + lane;
    float v = x[idx];
    u32 u  = __float_as_uint(v);
    u32 hb = (u + 0x7FFFu + ((u >> 16) & 1u)) >> 16;        // RNE to bf16
    float hf = __uint_as_float(hb << 16);
    float lf = v - hf;
    u32 ul = __float_as_uint(lf);
    u32 lb = (ul + 0x7FFFu + ((ul >> 16) & 1u)) >> 16;
    hi[idx] = (u16)hb;
    lo[idx] = (u16)lb;
    float s = v * v;
    #pragma unroll
    for (int m = 32; m >= 1; m >>= 1) s += __shfl_xor(s, m);
    if (lane == 0) sq[row] = s;
}

// ---------------------------------------------------------------------------
// Init: comp[v]=v, minEdge=INF, lossAcc=0, classDone=0.
// ---------------------------------------------------------------------------
__global__ void init_kernel(u32* __restrict__ comp, u64* __restrict__ minEdge,
                            float* __restrict__ lossAcc, u32* __restrict__ classDone) {
    int i = blockIdx.x * 256 + threadIdx.x;
    if (i < NCLS * NPT) {
        comp[i]    = (u32)(i & (NPT - 1));
        minEdge[i] = INF64;
    }
    if (i < NCLS) { lossAcc[i] = 0.0f; classDone[i] = 0u; }
}

// ---------------------------------------------------------------------------
// Kernel 2: fused Boruvka scan round, MFMA Gram recompute (no dist matrix).
// Block = 128x128 tile of one class. 4 waves, each wave: 32 rows x 128 cols.
// d2 = sq_i + sq_j - 2*(H.H + H.L + L.H), packed key = round21(d2)|col,
// masked by comp equality, row-min across cols, one atomicMin(u64) per row.
// Pass order is canonicalized by block orientation so d2(i,j)==d2(j,i) bitwise.
// ---------------------------------------------------------------------------
__global__ __launch_bounds__(256) void boruvka_scan_mfma(
    const u16* __restrict__ hi, const u16* __restrict__ lo,
    const float* __restrict__ sq, const u32* __restrict__ comp,
    u64* __restrict__ minEdge, const u32* __restrict__ classDone)
{
    const int c = blockIdx.z;
    if (classDone[c]) return;
    const int tj   = blockIdx.x;
    const int ti   = blockIdx.y;
    const int tid  = threadIdx.x;
    const int lane = tid & 63;
    const int w    = tid >> 6;
    const bool swap_ = (ti > tj);
    const bool diag  = (ti == tj);

    __shared__ u32   compR[128], compC[128];
    __shared__ float sqR[128],  sqC[128];
    if (tid < 128) {
        compR[tid] = comp[(size_t)c * NPT + ti * 128 + tid];
        sqR[tid]   = sq[(size_t)c * NPT + ti * 128 + tid];
    } else {
        int t = tid - 128;
        compC[t] = comp[(size_t)c * NPT + tj * 128 + t];
        sqC[t]   = sq[(size_t)c * NPT + tj * 128 + t];
    }
    __syncthreads();

    const size_t xbase = (size_t)c * NPT * DIM;
    const int    kq    = (lane >> 4) * 8;     // lane-group k offset (8 contiguous)
    const int    arow  = ti * 128 + w * 32 + (lane & 15);

    // A fragments: 2 row-tiles x 2 K-chunks, hi and lo
    bf16x8 Ah[2][2], Al[2][2];
    #pragma unroll
    for (int rt = 0; rt < 2; ++rt) {
        #pragma unroll
        for (int kk = 0; kk < 2; ++kk) {
            size_t off = xbase + (size_t)(arow + rt * 16) * DIM + kk * 32 + kq;
            Ah[rt][kk] = __builtin_bit_cast(bf16x8, *(const u32x4*)(hi + off));
            Al[rt][kk] = __builtin_bit_cast(bf16x8, *(const u32x4*)(lo + off));
        }
    }

    // per-output-slot row constants (C/D layout: row=(lane>>4)*4+reg, col=lane&15)
    float sqrow[2][4];
    u32   crow[2][4];
    #pragma unroll
    for (int rt = 0; rt < 2; ++rt)
        #pragma unroll
        for (int r = 0; r < 4; ++r) {
            int rl = w * 32 + rt * 16 + ((lane >> 4) << 2) + r;
            sqrow[rt][r] = sqR[rl];
            crow[rt][r]  = compR[rl];
        }

    u32 rm[2][4];
    #pragma unroll
    for (int rt = 0; rt < 2; ++rt)
        #pragma unroll
        for (int r = 0; r < 4; ++r) rm[rt][r] = INFK;

    #pragma unroll 1
    for (int ct = 0; ct < 8; ++ct) {
        const int colb = tj * 128 + ct * 16 + (lane & 15);
        bf16x8 Bh[2], Bl[2];
        #pragma unroll
        for (int kk = 0; kk < 2; ++kk) {
            size_t off = xbase + (size_t)colb * DIM + kk * 32 + kq;
            Bh[kk] = __builtin_bit_cast(bf16x8, *(const u32x4*)(hi + off));
            Bl[kk] = __builtin_bit_cast(bf16x8, *(const u32x4*)(lo + off));
        }
        u32   ccol = compC[ct * 16 + (lane & 15)];
        float sqc_ = sqC[ct * 16 + (lane & 15)];

        #pragma unroll
        for (int rt = 0; rt < 2; ++rt) {
            f32x4 accA = {0.f, 0.f, 0.f, 0.f};
            accA = MFMA16(Ah[rt][0], Bh[0], accA);
            accA = MFMA16(Ah[rt][1], Bh[1], accA);
            if (!swap_) {
                accA = MFMA16(Ah[rt][0], Bl[0], accA);
                accA = MFMA16(Ah[rt][1], Bl[1], accA);
                accA = MFMA16(Al[rt][0], Bh[0], accA);
                accA = MFMA16(Al[rt][1], Bh[1], accA);
            } else {
                accA = MFMA16(Al[rt][0], Bh[0], accA);
                accA = MFMA16(Al[rt][1], Bh[1], accA);
                accA = MFMA16(Ah[rt][0], Bl[0], accA);
                accA = MFMA16(Ah[rt][1], Bl[1], accA);
            }
            f32x4 accB = {0.f, 0.f, 0.f, 0.f};
            if (diag) {      // second orientation for the lower triangle
                accB = MFMA16(Ah[rt][0], Bh[0], accB);
                accB = MFMA16(Ah[rt][1], Bh[1], accB);
                accB = MFMA16(Al[rt][0], Bh[0], accB);
                accB = MFMA16(Al[rt][1], Bh[1], accB);
                accB = MFMA16(Ah[rt][0], Bl[0], accB);
                accB = MFMA16(Ah[rt][1], Bl[1], accB);
            }
            #pragma unroll
            for (int r = 0; r < 4; ++r) {
                int rl   = w * 32 + rt * 16 + ((lane >> 4) << 2) + r;
                int rowg = ti * 128 + rl;
                float g  = (diag && rowg > colb) ? accB[r] : accA[r];
                float d2 = fmaf(-2.0f, g, sqrow[rt][r] + sqc_);
                d2 = fmaxf(d2, 0.0f);
                u32 bk = (__float_as_uint(d2) + 0x400u) & 0xFFFFF800u;
                u32 k2 = bk | (u32)colb;
                k2 = (crow[rt][r] == ccol) ? INFK : k2;
                rm[rt][r] = min(rm[rt][r], k2);
            }
        }
    }

    // reduce row-min across the 16 cols (lanes sharing lane>>4 group)
    #pragma unroll
    for (int rt = 0; rt < 2; ++rt)
        #pragma unroll
        for (int r = 0; r < 4; ++r) {
            u32 b = rm[rt][r];
            #pragma unroll
            for (int m = 8; m >= 1; m >>= 1)
                b = min(b, (u32)__shfl_xor((int)b, m));
            if ((lane & 15) == 0 && b != INFK) {
                int rl   = w * 32 + rt * 16 + ((lane >> 4) << 2) + r;
                int rowg = ti * 128 + rl;
                int colg = (int)(b & 0x7FFu);
                u32 d21  = b >> 11;
                int mn = rowg < colg ? rowg : colg;
                int mx = rowg < colg ? colg : rowg;
                u64 key = ((u64)d21 << 22) | ((u64)mn << 11) | (u64)mx;
                atomicMin(&minEdge[(size_t)c * NPT + crow[rt][r]], key);
            }
        }
}

// ---------------------------------------------------------------------------
// Kernel 3: Boruvka merge. One block per class. Key d-field now holds rounded
// d2; sqrt applied here (once per accepted edge).
// ---------------------------------------------------------------------------
__global__ __launch_bounds__(256) void merge_kernel(u32* __restrict__ comp,
                                                    u64* __restrict__ minEdge,
                                                    float* __restrict__ lossAcc,
                                                    u32* __restrict__ classDone) {
    __shared__ u32   compL[NPT];
    __shared__ u32   parentL[NPT];
    __shared__ u64   edgeL[NPT];
    __shared__ float rw[256];
    __shared__ int   rc[256];
    __shared__ int   conv;

    const int c   = blockIdx.x;
    const int tid = threadIdx.x;
    if (classDone[c]) return;

    u32* compG = comp + (size_t)c * NPT;
    u64* edgeG = minEdge + (size_t)c * NPT;

    #pragma unroll
    for (int k = 0; k < NPT / 256; ++k) {
        int i = k * 256 + tid;
        compL[i]   = compG[i];
        parentL[i] = (u32)i;
        edgeL[i]   = edgeG[i];
    }
    if (tid == 0) conv = 1;
    __syncthreads();

    float myw = 0.0f;
    int   mycnt = 0;
    #pragma unroll
    for (int k = 0; k < NPT / 256; ++k) {
        int L = k * 256 + tid;
        u64 e = edgeL[L];
        if (e != INF64) {
            int mn = (int)((e >> 11) & 0x7FF);
            int mx = (int)(e & 0x7FF);
            u32 A = compL[mn], B = compL[mx];
            u32 O = (A == (u32)L) ? B : A;
            bool mutual = (edgeL[O] == e);
            if (!(mutual && (u32)L > O)) {
                parentL[L] = O;
                float d2 = __uint_as_float((u32)(e >> 22) << 11);
                myw += fabsf(sqrtf(d2) - 1.0f);
                mycnt += 1;
            }
        }
    }
    __syncthreads();

    // safety: break any residual 2-cycle (larger id resets to self)
    #pragma unroll
    for (int k = 0; k < NPT / 256; ++k) {
        int L = k * 256 + tid;
        u32 p1 = parentL[L];
        if (p1 != (u32)L && parentL[p1] == (u32)L && (u32)L > p1) parentL[L] = (u32)L;
    }
    __syncthreads();

    // pointer jumping: 11 doublings cover chains up to length 2048
    for (int it = 0; it < 11; ++it) {
        u32 np[NPT / 256];
        #pragma unroll
        for (int k = 0; k < NPT / 256; ++k) {
            int L = k * 256 + tid;
            np[k] = parentL[parentL[L]];
        }
        __syncthreads();
        #pragma unroll
        for (int k = 0; k < NPT / 256; ++k) parentL[k * 256 + tid] = np[k];
        __syncthreads();
    }

    u32 root0 = parentL[compL[0]];
    #pragma unroll
    for (int k = 0; k < NPT / 256; ++k) {
        int v = k * 256 + tid;
        u32 nc = parentL[compL[v]];
        compG[v] = nc;
        if (nc != root0) conv = 0;     // benign race: all writers write 0
        edgeG[v] = INF64;              // reset for next round
    }

    rw[tid] = myw; rc[tid] = mycnt;
    __syncthreads();
    for (int s = 128; s >= 1; s >>= 1) {
        if (tid < s) { rw[tid] += rw[tid + s]; rc[tid] += rc[tid + s]; }
        __syncthreads();
    }
    if (tid == 0) {
        lossAcc[c] += rw[0];
        if (conv || rc[0] == 0) classDone[c] = 1;
    }
}

// ---------------------------------------------------------------------------
// Finalize: out = sum_c lossAcc[c] / (NPT-1).
// ---------------------------------------------------------------------------
__global__ void final2_kernel(const float* __restrict__ lossAcc, float* __restrict__ out) {
    if (threadIdx.x == 0 && blockIdx.x == 0) {
        float s = 0.0f;
        for (int cc = 0; cc < NCLS; ++cc) s += lossAcc[cc] * (1.0f / (float)(NPT - 1));
        out[0] = s;
    }
}

// ---------------------------------------------------------------------------
// Fallback (ws too small): on-the-fly Prim, 1024 threads/class.
// ---------------------------------------------------------------------------
__global__ __launch_bounds__(1024) void prim_onfly_kernel(const float* __restrict__ x,
                                                          float* __restrict__ loss_out) {
    __shared__ float  redV[2][16];
    __shared__ int    redI[2][16];
    __shared__ float  finV[2];
    __shared__ int    finI[2];
    __shared__ float4 xjs[2][16];

    const int c    = blockIdx.x;
    const int tid  = threadIdx.x;
    const int lane = tid & 63;
    const int wid  = tid >> 6;
    const int v0   = tid * 2;
    const int v1   = tid * 2 + 1;

    float m0 = FINF, m1 = FINF;
    bool  t0 = (v0 == 0);
    bool  t1 = false;

    int   j = 0;
    int   p = 0;
    float loss = 0.0f;

    const float4* xc4 = (const float4*)(x + (size_t)c * NPT * DIM);

    for (int t = 0; t < NPT - 1; ++t) {
        if (tid < 16) xjs[p][tid] = xc4[(size_t)j * 16 + tid];
        __syncthreads();
        float a0 = 0.0f, a1 = 0.0f;
        #pragma unroll
        for (int k = 0; k < 16; ++k) {
            float4 xj = xjs[p][k];
            float4 q0 = xc4[(size_t)v0 * 16 + k];
            float4 q1 = xc4[(size_t)v1 * 16 + k];
            float dx;
            dx = xj.x - q0.x; a0 = fmaf(dx, dx, a0);
            dx = xj.y - q0.y; a0 = fmaf(dx, dx, a0);
            dx = xj.z - q0.z; a0 = fmaf(dx, dx, a0);
            dx = xj.w - q0.w; a0 = fmaf(dx, dx, a0);
            dx = xj.x - q1.x; a1 = fmaf(dx, dx, a1);
            dx = xj.y - q1.y; a1 = fmaf(dx, dx, a1);
            dx = xj.z - q1.z; a1 = fmaf(dx, dx, a1);
            dx = xj.w - q1.w; a1 = fmaf(dx, dx, a1);
        }
        float d0 = a0 > 0.0f ? sqrtf(a0) : 0.0f;
        float d1 = a1 > 0.0f ? sqrtf(a1) : 0.0f;

        if (!t0) m0 = fminf(m0, d0);
        if (!t1) m1 = fminf(m1, d1);

        float val; int idx;
        if (m0 <= m1) { val = m0; idx = v0; }
        else          { val = m1; idx = v1; }

        #pragma unroll
        for (int m = 32; m >= 1; m >>= 1) {
            float ov = __shfl_xor(val, m);
            int   oi = __shfl_xor(idx, m);
            if (ov < val || (ov == val && oi < idx)) { val = ov; idx = oi; }
        }
        if (lane == 0) { redV[p][wid] = val; redI[p][wid] = idx; }
        __syncthreads();

        if (wid == 0) {
            float v  = (lane < 16) ? redV[p][lane] : FINF;
            int   i2 = (lane < 16) ? redI[p][lane] : 0x7fffffff;
            #pragma unroll
            for (int m = 8; m >= 1; m >>= 1) {
                float ov = __shfl_xor(v, m);
                int   oi = __shfl_xor(i2, m);
                if (ov < v || (ov == v && oi < i2)) { v = ov; i2 = oi; }
            }
            if (lane == 0) { finV[p] = v; finI[p] = i2; }
        }
        __syncthreads();

        float bv = finV[p];
        j        = finI[p];
        if (tid == 0) loss += fabsf(bv - 1.0f);
        if (v0 == j) { t0 = true; m0 = FINF; }
        if (v1 == j) { t1 = true; m1 = FINF; }
        p ^= 1;
    }

    if (tid == 0) loss_out[c] = loss / (float)(NPT - 1);
}

__global__ void finalize_kernel(const float* __restrict__ loss, float* __restrict__ out) {
    if (threadIdx.x == 0 && blockIdx.x == 0) {
        float s = 0.0f;
        for (int c = 0; c < NCLS; ++c) s += loss[c];
        out[0] = s;
    }
}

extern "C" void kernel_launch(void* const* d_in, const int* in_sizes, int n_in,
                              void* d_out, int out_size, void* d_ws, size_t ws_size,
                              hipStream_t stream) {
    const float* x   = (const float*)d_in[0];
    float*       out = (float*)d_out;

    const size_t nv = (size_t)NCLS * NPT;
    const size_t nx = (size_t)NCLS * NPT * DIM;

    const size_t off_me   = 0;                                   // u64, 8-aligned
    const size_t off_hi   = off_me + nv * sizeof(u64);
    const size_t off_lo   = off_hi + nx * sizeof(u16);
    const size_t off_sq   = off_lo + nx * sizeof(u16);
    const size_t off_comp = off_sq + nv * sizeof(float);
    const size_t off_loss = off_comp + nv * sizeof(u32);
    const size_t off_done = off_loss + NCLS * sizeof(float);
    const size_t need     = off_done + NCLS * sizeof(u32);

    if (ws_size >= need) {
        u64*   minEdge = (u64*)((char*)d_ws + off_me);
        u16*   hi      = (u16*)((char*)d_ws + off_hi);
        u16*   lo      = (u16*)((char*)d_ws + off_lo);
        float* sq      = (float*)((char*)d_ws + off_sq);
        u32*   comp    = (u32*)((char*)d_ws + off_comp);
        float* lossAcc = (float*)((char*)d_ws + off_loss);
        u32*   done    = (u32*)((char*)d_ws + off_done);

        init_kernel<<<(int)((nv + 255) / 256), 256, 0, stream>>>(comp, minEdge, lossAcc, done);
        conv_norms_kernel<<<(NCLS * NPT) / 4, 256, 0, stream>>>(x, hi, lo, sq);
        for (int r = 0; r < 11; ++r) {
            boruvka_scan_mfma<<<dim3(NPT / 128, NPT / 128, NCLS), 256, 0, stream>>>(
                hi, lo, sq, comp, minEdge, done);
            merge_kernel<<<NCLS, 256, 0, stream>>>(comp, minEdge, lossAcc, done);
        }
        final2_kernel<<<1, 64, 0, stream>>>(lossAcc, out);
    } else {
        float* loss = (float*)d_ws;
        prim_onfly_kernel<<<NCLS, 1024, 0, stream>>>(x, loss);
        finalize_kernel<<<1, 64, 0, stream>>>(loss, out);
    }
}

// Round 5
// 208.706 us; speedup vs baseline: 5.7165x; 5.7165x over previous
//
#include <hip/hip_runtime.h>

#define NCLS 8
#define NPT  2048
#define DIM  64
#define FINF 3.402823466e38f
#define INFK 0xFFFFFFFFu
#define INF64 0xFFFFFFFFFFFFFFFFull

typedef unsigned int u32;
typedef unsigned long long u64;
typedef unsigned short u16;
typedef __bf16 bf16_t;
typedef __attribute__((ext_vector_type(8))) bf16_t bf16x8;
typedef __attribute__((ext_vector_type(4))) float f32x4;
typedef __attribute__((ext_vector_type(4))) u32 u32x4;

#define MFMA16(a, b, c) __builtin_amdgcn_mfma_f32_16x16x32_bf16((a), (b), (c), 0, 0, 0)

// ---------------------------------------------------------------------------
// Kernel 1: fp32 -> bf16 hi/lo split (x = hi + lo) + exact fp32 row norms.
// ---------------------------------------------------------------------------
__global__ void conv_norms_kernel(const float* __restrict__ x, u16* __restrict__ hi,
                                  u16* __restrict__ lo, float* __restrict__ sq) {
    int row  = blockIdx.x * 4 + (threadIdx.x >> 6);
    int lane = threadIdx.x & 63;
    size_t idx = (size_t)row * DIM + lane;
    float v = x[idx];
    u32 u  = __float_as_uint(v);
    u32 hb = (u + 0x7FFFu + ((u >> 16) & 1u)) >> 16;        // RNE to bf16
    float hf = __uint_as_float(hb << 16);
    float lf = v - hf;
    u32 ul = __float_as_uint(lf);
    u32 lb = (ul + 0x7FFFu + ((ul >> 16) & 1u)) >> 16;
    hi[idx] = (u16)hb;
    lo[idx] = (u16)lb;
    float s = v * v;
    #pragma unroll
    for (int m = 32; m >= 1; m >>= 1) s += __shfl_xor(s, m);
    if (lane == 0) sq[row] = s;
}

// ---------------------------------------------------------------------------
// Init: comp[v]=v, minEdge=INF, lossAcc=0, classDone=0.
// ---------------------------------------------------------------------------
__global__ void init_kernel(u32* __restrict__ comp, u64* __restrict__ minEdge,
                            float* __restrict__ lossAcc, u32* __restrict__ classDone) {
    int i = blockIdx.x * 256 + threadIdx.x;
    if (i < NCLS * NPT) {
        comp[i]    = (u32)(i & (NPT - 1));
        minEdge[i] = INF64;
    }
    if (i < NCLS) { lossAcc[i] = 0.0f; classDone[i] = 0u; }
}

// ---------------------------------------------------------------------------
// Kernel 2: fused Boruvka scan, MFMA Gram recompute.
// Block = 128 rows x 512 cols (col-split cs=0..3), grid (4, 16, NCLS).
// Per-row winners pre-reduced into an LDS per-component table (ds_min_u64),
// flushed once per block -> global atomic fan-in is tiny even when comp
// collapses to few roots (the round-4 612us lesson).
// Pass order canonicalized per 128-tile pair so d2(i,j)==d2(j,i) bitwise.
// ---------------------------------------------------------------------------
__global__ __launch_bounds__(256) void scan2_kernel(
    const u16* __restrict__ hi, const u16* __restrict__ lo,
    const float* __restrict__ sq, const u32* __restrict__ comp,
    u64* __restrict__ minEdge, const u32* __restrict__ classDone)
{
    const int c = blockIdx.z;
    if (classDone[c]) return;
    const int cs   = blockIdx.x;      // col split (512 cols)
    const int rb   = blockIdx.y;      // row block (128 rows)
    const int tid  = threadIdx.x;
    const int lane = tid & 63;
    const int w    = tid >> 6;

    __shared__ u32   compL[NPT];
    __shared__ float sqL[NPT];
    __shared__ u64   minT[NPT];

    const u32*   compG = comp + (size_t)c * NPT;
    const float* sqG   = sq + (size_t)c * NPT;
    #pragma unroll
    for (int k = 0; k < NPT / 256; ++k) {
        int i = k * 256 + tid;
        compL[i] = compG[i];
        sqL[i]   = sqG[i];
        minT[i]  = INF64;
    }
    __syncthreads();

    const size_t xbase = (size_t)c * NPT * DIM;
    const int    kq    = (lane >> 4) * 8;
    const int    arow  = rb * 128 + w * 32 + (lane & 15);

    bf16x8 Ah[2][2], Al[2][2];
    #pragma unroll
    for (int rt = 0; rt < 2; ++rt) {
        #pragma unroll
        for (int kk = 0; kk < 2; ++kk) {
            size_t off = xbase + (size_t)(arow + rt * 16) * DIM + kk * 32 + kq;
            Ah[rt][kk] = __builtin_bit_cast(bf16x8, *(const u32x4*)(hi + off));
            Al[rt][kk] = __builtin_bit_cast(bf16x8, *(const u32x4*)(lo + off));
        }
    }

    // per-output-slot row constants (C/D: row=(lane>>4)*4+reg, col=lane&15)
    int   rowg_[2][4];
    float sqrow[2][4];
    u32   crow[2][4];
    #pragma unroll
    for (int rt = 0; rt < 2; ++rt)
        #pragma unroll
        for (int r = 0; r < 4; ++r) {
            int rg = rb * 128 + w * 32 + rt * 16 + ((lane >> 4) << 2) + r;
            rowg_[rt][r] = rg;
            sqrow[rt][r] = sqL[rg];
            crow[rt][r]  = compL[rg];
        }

    u32 rm[2][4];
    #pragma unroll
    for (int rt = 0; rt < 2; ++rt)
        #pragma unroll
        for (int r = 0; r < 4; ++r) rm[rt][r] = INFK;

    #pragma unroll 2
    for (int ct = 0; ct < 32; ++ct) {
        const int colb0 = cs * 512 + ct * 16;
        const int colb  = colb0 + (lane & 15);
        const int tj128 = colb0 >> 7;
        const bool swap_ = (rb > tj128);
        const bool diag  = (rb == tj128);

        bf16x8 Bh[2], Bl[2];
        #pragma unroll
        for (int kk = 0; kk < 2; ++kk) {
            size_t off = xbase + (size_t)colb * DIM + kk * 32 + kq;
            Bh[kk] = __builtin_bit_cast(bf16x8, *(const u32x4*)(hi + off));
            Bl[kk] = __builtin_bit_cast(bf16x8, *(const u32x4*)(lo + off));
        }
        u32   ccol = compL[colb];
        float sqc_ = sqL[colb];

        #pragma unroll
        for (int rt = 0; rt < 2; ++rt) {
            f32x4 accA = {0.f, 0.f, 0.f, 0.f};
            accA = MFMA16(Ah[rt][0], Bh[0], accA);
            accA = MFMA16(Ah[rt][1], Bh[1], accA);
            if (!swap_) {
                accA = MFMA16(Ah[rt][0], Bl[0], accA);
                accA = MFMA16(Ah[rt][1], Bl[1], accA);
                accA = MFMA16(Al[rt][0], Bh[0], accA);
                accA = MFMA16(Al[rt][1], Bh[1], accA);
            } else {
                accA = MFMA16(Al[rt][0], Bh[0], accA);
                accA = MFMA16(Al[rt][1], Bh[1], accA);
                accA = MFMA16(Ah[rt][0], Bl[0], accA);
                accA = MFMA16(Ah[rt][1], Bl[1], accA);
            }
            f32x4 accB = {0.f, 0.f, 0.f, 0.f};
            if (diag) {      // lower-triangle orientation inside diagonal tile
                accB = MFMA16(Ah[rt][0], Bh[0], accB);
                accB = MFMA16(Ah[rt][1], Bh[1], accB);
                accB = MFMA16(Al[rt][0], Bh[0], accB);
                accB = MFMA16(Al[rt][1], Bh[1], accB);
                accB = MFMA16(Ah[rt][0], Bl[0], accB);
                accB = MFMA16(Ah[rt][1], Bl[1], accB);
            }
            #pragma unroll
            for (int r = 0; r < 4; ++r) {
                float g  = (diag && rowg_[rt][r] > colb) ? accB[r] : accA[r];
                float d2 = fmaf(-2.0f, g, sqrow[rt][r] + sqc_);
                d2 = fmaxf(d2, 0.0f);
                u32 bk = (__float_as_uint(d2) + 0x400u) & 0xFFFFF800u;
                u32 k2 = bk | (u32)colb;
                k2 = (crow[rt][r] == ccol) ? INFK : k2;
                rm[rt][r] = min(rm[rt][r], k2);
            }
        }
    }

    // reduce row-min across the 16 col-lanes, then LDS per-comp table
    #pragma unroll
    for (int rt = 0; rt < 2; ++rt)
        #pragma unroll
        for (int r = 0; r < 4; ++r) {
            u32 b = rm[rt][r];
            #pragma unroll
            for (int m = 8; m >= 1; m >>= 1)
                b = min(b, (u32)__shfl_xor((int)b, m));
            if ((lane & 15) == 0 && b != INFK) {
                int rowg = rowg_[rt][r];
                int colg = (int)(b & 0x7FFu);
                u32 d21  = b >> 11;
                int mn = rowg < colg ? rowg : colg;
                int mx = rowg < colg ? colg : rowg;
                u64 key = ((u64)d21 << 22) | ((u64)mn << 11) | (u64)mx;
                atomicMin(&minT[crow[rt][r]], key);
            }
        }
    __syncthreads();

    // flush: one global atomic per distinct component present in this block
    u64* edgeG = minEdge + (size_t)c * NPT;
    #pragma unroll
    for (int k = 0; k < NPT / 256; ++k) {
        int i = k * 256 + tid;
        u64 e = minT[i];
        if (e != INF64) atomicMin(&edgeG[i], e);
    }
}

// ---------------------------------------------------------------------------
// Kernel 3: Boruvka merge. One block per class. sqrt applied here.
// ---------------------------------------------------------------------------
__global__ __launch_bounds__(256) void merge_kernel(u32* __restrict__ comp,
                                                    u64* __restrict__ minEdge,
                                                    float* __restrict__ lossAcc,
                                                    u32* __restrict__ classDone) {
    __shared__ u32   compL[NPT];
    __shared__ u32   parentL[NPT];
    __shared__ u64   edgeL[NPT];
    __shared__ float rw[256];
    __shared__ int   rc[256];
    __shared__ int   conv;

    const int c   = blockIdx.x;
    const int tid = threadIdx.x;
    if (classDone[c]) return;

    u32* compG = comp + (size_t)c * NPT;
    u64* edgeG = minEdge + (size_t)c * NPT;

    #pragma unroll
    for (int k = 0; k < NPT / 256; ++k) {
        int i = k * 256 + tid;
        compL[i]   = compG[i];
        parentL[i] = (u32)i;
        edgeL[i]   = edgeG[i];
    }
    if (tid == 0) conv = 1;
    __syncthreads();

    float myw = 0.0f;
    int   mycnt = 0;
    #pragma unroll
    for (int k = 0; k < NPT / 256; ++k) {
        int L = k * 256 + tid;
        u64 e = edgeL[L];
        if (e != INF64) {
            int mn = (int)((e >> 11) & 0x7FF);
            int mx = (int)(e & 0x7FF);
            u32 A = compL[mn], B = compL[mx];
            u32 O = (A == (u32)L) ? B : A;
            bool mutual = (edgeL[O] == e);
            if (!(mutual && (u32)L > O)) {
                parentL[L] = O;
                float d2 = __uint_as_float((u32)(e >> 22) << 11);
                myw += fabsf(sqrtf(d2) - 1.0f);
                mycnt += 1;
            }
        }
    }
    __syncthreads();

    // safety: break any residual 2-cycle (larger id resets to self)
    #pragma unroll
    for (int k = 0; k < NPT / 256; ++k) {
        int L = k * 256 + tid;
        u32 p1 = parentL[L];
        if (p1 != (u32)L && parentL[p1] == (u32)L && (u32)L > p1) parentL[L] = (u32)L;
    }
    __syncthreads();

    // pointer jumping: 11 doublings cover chains up to length 2048
    for (int it = 0; it < 11; ++it) {
        u32 np[NPT / 256];
        #pragma unroll
        for (int k = 0; k < NPT / 256; ++k) {
            int L = k * 256 + tid;
            np[k] = parentL[parentL[L]];
        }
        __syncthreads();
        #pragma unroll
        for (int k = 0; k < NPT / 256; ++k) parentL[k * 256 + tid] = np[k];
        __syncthreads();
    }

    u32 root0 = parentL[compL[0]];
    #pragma unroll
    for (int k = 0; k < NPT / 256; ++k) {
        int v = k * 256 + tid;
        u32 nc = parentL[compL[v]];
        compG[v] = nc;
        if (nc != root0) conv = 0;     // benign race: all writers write 0
        edgeG[v] = INF64;              // reset for next round
    }

    rw[tid] = myw; rc[tid] = mycnt;
    __syncthreads();
    for (int s = 128; s >= 1; s >>= 1) {
        if (tid < s) { rw[tid] += rw[tid + s]; rc[tid] += rc[tid + s]; }
        __syncthreads();
    }
    if (tid == 0) {
        lossAcc[c] += rw[0];
        if (conv || rc[0] == 0) classDone[c] = 1;
    }
}

// ---------------------------------------------------------------------------
// Finalize: out = sum_c lossAcc[c] / (NPT-1).
// ---------------------------------------------------------------------------
__global__ void final2_kernel(const float* __restrict__ lossAcc, float* __restrict__ out) {
    if (threadIdx.x == 0 && blockIdx.x == 0) {
        float s = 0.0f;
        for (int cc = 0; cc < NCLS; ++cc) s += lossAcc[cc] * (1.0f / (float)(NPT - 1));
        out[0] = s;
    }
}

// ---------------------------------------------------------------------------
// Fallback (ws too small): on-the-fly Prim, 1024 threads/class.
// ---------------------------------------------------------------------------
__global__ __launch_bounds__(1024) void prim_onfly_kernel(const float* __restrict__ x,
                                                          float* __restrict__ loss_out) {
    __shared__ float  redV[2][16];
    __shared__ int    redI[2][16];
    __shared__ float  finV[2];
    __shared__ int    finI[2];
    __shared__ float4 xjs[2][16];

    const int c    = blockIdx.x;
    const int tid  = threadIdx.x;
    const int lane = tid & 63;
    const int wid  = tid >> 6;
    const int v0   = tid * 2;
    const int v1   = tid * 2 + 1;

    float m0 = FINF, m1 = FINF;
    bool  t0 = (v0 == 0);
    bool  t1 = false;

    int   j = 0;
    int   p = 0;
    float loss = 0.0f;

    const float4* xc4 = (const float4*)(x + (size_t)c * NPT * DIM);

    for (int t = 0; t < NPT - 1; ++t) {
        if (tid < 16) xjs[p][tid] = xc4[(size_t)j * 16 + tid];
        __syncthreads();
        float a0 = 0.0f, a1 = 0.0f;
        #pragma unroll
        for (int k = 0; k < 16; ++k) {
            float4 xj = xjs[p][k];
            float4 q0 = xc4[(size_t)v0 * 16 + k];
            float4 q1 = xc4[(size_t)v1 * 16 + k];
            float dx;
            dx = xj.x - q0.x; a0 = fmaf(dx, dx, a0);
            dx = xj.y - q0.y; a0 = fmaf(dx, dx, a0);
            dx = xj.z - q0.z; a0 = fmaf(dx, dx, a0);
            dx = xj.w - q0.w; a0 = fmaf(dx, dx, a0);
            dx = xj.x - q1.x; a1 = fmaf(dx, dx, a1);
            dx = xj.y - q1.y; a1 = fmaf(dx, dx, a1);
            dx = xj.z - q1.z; a1 = fmaf(dx, dx, a1);
            dx = xj.w - q1.w; a1 = fmaf(dx, dx, a1);
        }
        float d0 = a0 > 0.0f ? sqrtf(a0) : 0.0f;
        float d1 = a1 > 0.0f ? sqrtf(a1) : 0.0f;

        if (!t0) m0 = fminf(m0, d0);
        if (!t1) m1 = fminf(m1, d1);

        float val; int idx;
        if (m0 <= m1) { val = m0; idx = v0; }
        else          { val = m1; idx = v1; }

        #pragma unroll
        for (int m = 32; m >= 1; m >>= 1) {
            float ov = __shfl_xor(val, m);
            int   oi = __shfl_xor(idx, m);
            if (ov < val || (ov == val && oi < idx)) { val = ov; idx = oi; }
        }
        if (lane == 0) { redV[p][wid] = val; redI[p][wid] = idx; }
        __syncthreads();

        if (wid == 0) {
            float v  = (lane < 16) ? redV[p][lane] : FINF;
            int   i2 = (lane < 16) ? redI[p][lane] : 0x7fffffff;
            #pragma unroll
            for (int m = 8; m >= 1; m >>= 1) {
                float ov = __shfl_xor(v, m);
                int   oi = __shfl_xor(i2, m);
                if (ov < v || (ov == v && oi < i2)) { v = ov; i2 = oi; }
            }
            if (lane == 0) { finV[p] = v; finI[p] = i2; }
        }
        __syncthreads();

        float bv = finV[p];
        j        = finI[p];
        if (tid == 0) loss += fabsf(bv - 1.0f);
        if (v0 == j) { t0 = true; m0 = FINF; }
        if (v1 == j) { t1 = true; m1 = FINF; }
        p ^= 1;
    }

    if (tid == 0) loss_out[c] = loss / (float)(NPT - 1);
}

__global__ void finalize_kernel(const float* __restrict__ loss, float* __restrict__ out) {
    if (threadIdx.x == 0 && blockIdx.x == 0) {
        float s = 0.0f;
        for (int c = 0; c < NCLS; ++c) s += loss[c];
        out[0] = s;
    }
}

extern "C" void kernel_launch(void* const* d_in, const int* in_sizes, int n_in,
                              void* d_out, int out_size, void* d_ws, size_t ws_size,
                              hipStream_t stream) {
    const float* x   = (const float*)d_in[0];
    float*       out = (float*)d_out;

    const size_t nv = (size_t)NCLS * NPT;
    const size_t nx = (size_t)NCLS * NPT * DIM;

    const size_t off_me   = 0;                                   // u64, 8-aligned
    const size_t off_hi   = off_me + nv * sizeof(u64);
    const size_t off_lo   = off_hi + nx * sizeof(u16);
    const size_t off_sq   = off_lo + nx * sizeof(u16);
    const size_t off_comp = off_sq + nv * sizeof(float);
    const size_t off_loss = off_comp + nv * sizeof(u32);
    const size_t off_done = off_loss + NCLS * sizeof(float);
    const size_t need     = off_done + NCLS * sizeof(u32);

    if (ws_size >= need) {
        u64*   minEdge = (u64*)((char*)d_ws + off_me);
        u16*   hi      = (u16*)((char*)d_ws + off_hi);
        u16*   lo      = (u16*)((char*)d_ws + off_lo);
        float* sq      = (float*)((char*)d_ws + off_sq);
        u32*   comp    = (u32*)((char*)d_ws + off_comp);
        float* lossAcc = (float*)((char*)d_ws + off_loss);
        u32*   done    = (u32*)((char*)d_ws + off_done);

        init_kernel<<<(int)((nv + 255) / 256), 256, 0, stream>>>(comp, minEdge, lossAcc, done);
        conv_norms_kernel<<<(NCLS * NPT) / 4, 256, 0, stream>>>(x, hi, lo, sq);
        for (int r = 0; r < 11; ++r) {
            scan2_kernel<<<dim3(4, NPT / 128, NCLS), 256, 0, stream>>>(
                hi, lo, sq, comp, minEdge, done);
            merge_kernel<<<NCLS, 256, 0, stream>>>(comp, minEdge, lossAcc, done);
        }
        final2_kernel<<<1, 64, 0, stream>>>(lossAcc, out);
    } else {
        float* loss = (float*)d_ws;
        prim_onfly_kernel<<<NCLS, 1024, 0, stream>>>(x, loss);
        finalize_kernel<<<1, 64, 0, stream>>>(loss, out);
    }
}

// Round 7
// 142.520 us; speedup vs baseline: 8.3713x; 1.4644x over previous
//
#include <hip/hip_runtime.h>

#define NCLS 8
#define NPT  2048
#define DIM  64
#define FINF 3.402823466e38f
#define INFK 0xFFFFFFFFu
#define INF64 0xFFFFFFFFFFFFFFFFull

typedef unsigned int u32;
typedef unsigned long long u64;
typedef unsigned short u16;
typedef _Float16 f16_t;
typedef __attribute__((ext_vector_type(8))) f16_t f16x8;
typedef __attribute__((ext_vector_type(4))) float f32x4;
typedef __attribute__((ext_vector_type(4))) u32 u32x4;

#define MFMAH(a, b, c) __builtin_amdgcn_mfma_f32_16x16x32_f16((a), (b), (c), 0, 0, 0)

// ---------------------------------------------------------------------------
// Kernel 1: fp32 -> fp16 convert + exact fp32 row norms + Boruvka state init.
// One wave per row (DIM==64), 4 rows per block.
// ---------------------------------------------------------------------------
__global__ void convinit_kernel(const float* __restrict__ x, u16* __restrict__ xh,
                                float* __restrict__ sq, u32* __restrict__ comp,
                                u64* __restrict__ minEdge, float* __restrict__ lossAcc,
                                u32* __restrict__ done) {
    int row  = blockIdx.x * 4 + (threadIdx.x >> 6);
    int lane = threadIdx.x & 63;
    size_t idx = (size_t)row * DIM + lane;
    float v = x[idx];
    xh[idx] = __builtin_bit_cast(u16, (f16_t)v);   // RNE
    float s = v * v;
    #pragma unroll
    for (int m = 32; m >= 1; m >>= 1) s += __shfl_xor(s, m);
    if (lane == 0) {
        sq[row]      = s;
        comp[row]    = (u32)(row & (NPT - 1));
        minEdge[row] = INF64;
        if (row < NCLS) { lossAcc[row] = 0.0f; done[row] = 0u; }
    }
}

// ---------------------------------------------------------------------------
// Kernel 2: fused Boruvka scan, single-pass fp16 MFMA Gram recompute.
// Block = 128 rows x 512 cols (grid 4 x 16 x NCLS). Bitwise-symmetric d2
// (fp16 products commute, fixed HW k-order, commutative fp32 sq add) -> the
// exact-match mutual-edge dedup needs no pass-order canonicalization.
// Per-row winners pre-reduced in an LDS per-component table (round-5 lesson:
// global same-line atomic fan-in must stay tiny in late rounds).
// ---------------------------------------------------------------------------
__global__ __launch_bounds__(256) void scan2h_kernel(
    const u16* __restrict__ xh, const float* __restrict__ sq,
    const u32* __restrict__ comp, u64* __restrict__ minEdge,
    const u32* __restrict__ classDone)
{
    const int c = blockIdx.z;
    if (classDone[c]) return;
    const int cs   = blockIdx.x;      // col split (512 cols)
    const int rb   = blockIdx.y;      // row block (128 rows)
    const int tid  = threadIdx.x;
    const int lane = tid & 63;
    const int w    = tid >> 6;

    __shared__ u32   compL[NPT];
    __shared__ float sqL[NPT];
    __shared__ u64   minT[NPT];

    const u32*   compG = comp + (size_t)c * NPT;
    const float* sqG   = sq + (size_t)c * NPT;
    #pragma unroll
    for (int k = 0; k < NPT / 256; ++k) {
        int i = k * 256 + tid;
        compL[i] = compG[i];
        sqL[i]   = sqG[i];
        minT[i]  = INF64;
    }
    __syncthreads();

    const size_t xbase = (size_t)c * NPT * DIM;
    const int    kq    = (lane >> 4) * 8;
    const int    arow  = rb * 128 + w * 32 + (lane & 15);

    f16x8 Ah[2][2];
    #pragma unroll
    for (int rt = 0; rt < 2; ++rt)
        #pragma unroll
        for (int kk = 0; kk < 2; ++kk) {
            size_t off = xbase + (size_t)(arow + rt * 16) * DIM + kk * 32 + kq;
            Ah[rt][kk] = __builtin_bit_cast(f16x8, *(const u32x4*)(xh + off));
        }

    // per-output-slot row constants (C/D: row=(lane>>4)*4+reg, col=lane&15)
    int   rowg_[2][4];
    float sqrow[2][4];
    u32   crow[2][4];
    #pragma unroll
    for (int rt = 0; rt < 2; ++rt)
        #pragma unroll
        for (int r = 0; r < 4; ++r) {
            int rg = rb * 128 + w * 32 + rt * 16 + ((lane >> 4) << 2) + r;
            rowg_[rt][r] = rg;
            sqrow[rt][r] = sqL[rg];
            crow[rt][r]  = compL[rg];
        }

    u32 rm[2][4];
    #pragma unroll
    for (int rt = 0; rt < 2; ++rt)
        #pragma unroll
        for (int r = 0; r < 4; ++r) rm[rt][r] = INFK;

    #pragma unroll 2
    for (int ct = 0; ct < 32; ++ct) {
        const int colb = cs * 512 + ct * 16 + (lane & 15);
        f16x8 Bh[2];
        #pragma unroll
        for (int kk = 0; kk < 2; ++kk) {
            size_t off = xbase + (size_t)colb * DIM + kk * 32 + kq;
            Bh[kk] = __builtin_bit_cast(f16x8, *(const u32x4*)(xh + off));
        }
        u32   ccol = compL[colb];
        float sqc_ = sqL[colb];

        #pragma unroll
        for (int rt = 0; rt < 2; ++rt) {
            f32x4 acc = {0.f, 0.f, 0.f, 0.f};
            acc = MFMAH(Ah[rt][0], Bh[0], acc);
            acc = MFMAH(Ah[rt][1], Bh[1], acc);
            #pragma unroll
            for (int r = 0; r < 4; ++r) {
                float d2 = fmaf(-2.0f, acc[r], sqrow[rt][r] + sqc_);
                d2 = fmaxf(d2, 0.0f);
                u32 bk = (__float_as_uint(d2) + 0x400u) & 0xFFFFF800u;  // RNE 21-bit
                u32 k2 = bk | (u32)colb;
                k2 = (crow[rt][r] == ccol) ? INFK : k2;   // masks self too
                rm[rt][r] = min(rm[rt][r], k2);
            }
        }
    }

    // reduce row-min across the 16 col-lanes, then LDS per-comp table
    #pragma unroll
    for (int rt = 0; rt < 2; ++rt)
        #pragma unroll
        for (int r = 0; r < 4; ++r) {
            u32 b = rm[rt][r];
            #pragma unroll
            for (int m = 8; m >= 1; m >>= 1)
                b = min(b, (u32)__shfl_xor((int)b, m));
            if ((lane & 15) == 0 && b != INFK) {
                int rowg = rowg_[rt][r];
                int colg = (int)(b & 0x7FFu);
                u32 d21  = b >> 11;
                int mn = rowg < colg ? rowg : colg;
                int mx = rowg < colg ? colg : rowg;
                u64 key = ((u64)d21 << 22) | ((u64)mn << 11) | (u64)mx;
                atomicMin(&minT[crow[rt][r]], key);
            }
        }
    __syncthreads();

    // flush: one global atomic per distinct component present in this block
    u64* edgeG = minEdge + (size_t)c * NPT;
    #pragma unroll
    for (int k = 0; k < NPT / 256; ++k) {
        int i = k * 256 + tid;
        u64 e = minT[i];
        if (e != INF64) atomicMin(&edgeG[i], e);
    }
}

// ---------------------------------------------------------------------------
// Kernel 3: Boruvka merge. One block per class. sqrt applied here.
// ---------------------------------------------------------------------------
__global__ __launch_bounds__(256) void merge_kernel(u32* __restrict__ comp,
                                                    u64* __restrict__ minEdge,
                                                    float* __restrict__ lossAcc,
                                                    u32* __restrict__ classDone) {
    __shared__ u32   compL[NPT];
    __shared__ u32   parentL[NPT];
    __shared__ u64   edgeL[NPT];
    __shared__ float rw[256];
    __shared__ int   rc[256];
    __shared__ int   conv;

    const int c   = blockIdx.x;
    const int tid = threadIdx.x;
    if (classDone[c]) return;

    u32* compG = comp + (size_t)c * NPT;
    u64* edgeG = minEdge + (size_t)c * NPT;

    #pragma unroll
    for (int k = 0; k < NPT / 256; ++k) {
        int i = k * 256 + tid;
        compL[i]   = compG[i];
        parentL[i] = (u32)i;
        edgeL[i]   = edgeG[i];
    }
    if (tid == 0) conv = 1;
    __syncthreads();

    float myw = 0.0f;
    int   mycnt = 0;
    #pragma unroll
    for (int k = 0; k < NPT / 256; ++k) {
        int L = k * 256 + tid;
        u64 e = edgeL[L];
        if (e != INF64) {
            int mn = (int)((e >> 11) & 0x7FF);
            int mx = (int)(e & 0x7FF);
            u32 A = compL[mn], B = compL[mx];
            u32 O = (A == (u32)L) ? B : A;
            bool mutual = (edgeL[O] == e);
            if (!(mutual && (u32)L > O)) {
                parentL[L] = O;
                float d2 = __uint_as_float((u32)(e >> 22) << 11);
                myw += fabsf(sqrtf(d2) - 1.0f);
                mycnt += 1;
            }
        }
    }
    __syncthreads();

    // safety: break any residual 2-cycle (larger id resets to self)
    #pragma unroll
    for (int k = 0; k < NPT / 256; ++k) {
        int L = k * 256 + tid;
        u32 p1 = parentL[L];
        if (p1 != (u32)L && parentL[p1] == (u32)L && (u32)L > p1) parentL[L] = (u32)L;
    }
    __syncthreads();

    // pointer jumping: 11 doublings cover chains up to length 2048
    for (int it = 0; it < 11; ++it) {
        u32 np[NPT / 256];
        #pragma unroll
        for (int k = 0; k < NPT / 256; ++k) {
            int L = k * 256 + tid;
            np[k] = parentL[parentL[L]];
        }
        __syncthreads();
        #pragma unroll
        for (int k = 0; k < NPT / 256; ++k) parentL[k * 256 + tid] = np[k];
        __syncthreads();
    }

    u32 root0 = parentL[compL[0]];
    #pragma unroll
    for (int k = 0; k < NPT / 256; ++k) {
        int v = k * 256 + tid;
        u32 nc = parentL[compL[v]];
        compG[v] = nc;
        if (nc != root0) conv = 0;     // benign race: all writers write 0
        edgeG[v] = INF64;              // reset for next round
    }

    rw[tid] = myw; rc[tid] = mycnt;
    __syncthreads();
    for (int s = 128; s >= 1; s >>= 1) {
        if (tid < s) { rw[tid] += rw[tid + s]; rc[tid] += rc[tid + s]; }
        __syncthreads();
    }
    if (tid == 0) {
        lossAcc[c] += rw[0];
        if (conv || rc[0] == 0) classDone[c] = 1;
    }
}

// ---------------------------------------------------------------------------
// Finalize: out = sum_c lossAcc[c] / (NPT-1).
// ---------------------------------------------------------------------------
__global__ void final2_kernel(const float* __restrict__ lossAcc, float* __restrict__ out) {
    if (threadIdx.x == 0 && blockIdx.x == 0) {
        float s = 0.0f;
        for (int cc = 0; cc < NCLS; ++cc) s += lossAcc[cc] * (1.0f / (float)(NPT - 1));
        out[0] = s;
    }
}

// ---------------------------------------------------------------------------
// Fallback (ws too small): on-the-fly Prim, 1024 threads/class.
// ---------------------------------------------------------------------------
__global__ __launch_bounds__(1024) void prim_onfly_kernel(const float* __restrict__ x,
                                                          float* __restrict__ loss_out) {
    __shared__ float  redV[2][16];
    __shared__ int    redI[2][16];
    __shared__ float  finV[2];
    __shared__ int    finI[2];
    __shared__ float4 xjs[2][16];

    const int c    = blockIdx.x;
    const int tid  = threadIdx.x;
    const int lane = tid & 63;
    const int wid  = tid >> 6;
    const int v0   = tid * 2;
    const int v1   = tid * 2 + 1;

    float m0 = FINF, m1 = FINF;
    bool  t0 = (v0 == 0);
    bool  t1 = false;

    int   j = 0;
    int   p = 0;
    float loss = 0.0f;

    const float4* xc4 = (const float4*)(x + (size_t)c * NPT * DIM);

    for (int t = 0; t < NPT - 1; ++t) {
        if (tid < 16) xjs[p][tid] = xc4[(size_t)j * 16 + tid];
        __syncthreads();
        float a0 = 0.0f, a1 = 0.0f;
        #pragma unroll
        for (int k = 0; k < 16; ++k) {
            float4 xj = xjs[p][k];
            float4 q0 = xc4[(size_t)v0 * 16 + k];
            float4 q1 = xc4[(size_t)v1 * 16 + k];
            float dx;
            dx = xj.x - q0.x; a0 = fmaf(dx, dx, a0);
            dx = xj.y - q0.y; a0 = fmaf(dx, dx, a0);
            dx = xj.z - q0.z; a0 = fmaf(dx, dx, a0);
            dx = xj.w - q0.w; a0 = fmaf(dx, dx, a0);
            dx = xj.x - q1.x; a1 = fmaf(dx, dx, a1);
            dx = xj.y - q1.y; a1 = fmaf(dx, dx, a1);
            dx = xj.z - q1.z; a1 = fmaf(dx, dx, a1);
            dx = xj.w - q1.w; a1 = fmaf(dx, dx, a1);
        }
        float d0 = a0 > 0.0f ? sqrtf(a0) : 0.0f;
        float d1 = a1 > 0.0f ? sqrtf(a1) : 0.0f;

        if (!t0) m0 = fminf(m0, d0);
        if (!t1) m1 = fminf(m1, d1);

        float val; int idx;
        if (m0 <= m1) { val = m0; idx = v0; }
        else          { val = m1; idx = v1; }

        #pragma unroll
        for (int m = 32; m >= 1; m >>= 1) {
            float ov = __shfl_xor(val, m);
            int   oi = __shfl_xor(idx, m);
            if (ov < val || (ov == val && oi < idx)) { val = ov; idx = oi; }
        }
        if (lane == 0) { redV[p][wid] = val; redI[p][wid] = idx; }
        __syncthreads();

        if (wid == 0) {
            float v  = (lane < 16) ? redV[p][lane] : FINF;
            int   i2 = (lane < 16) ? redI[p][lane] : 0x7fffffff;
            #pragma unroll
            for (int m = 8; m >= 1; m >>= 1) {
                float ov = __shfl_xor(v, m);
                int   oi = __shfl_xor(i2, m);
                if (ov < v || (ov == v && oi < i2)) { v = ov; i2 = oi; }
            }
            if (lane == 0) { finV[p] = v; finI[p] = i2; }
        }
        __syncthreads();

        float bv = finV[p];
        j        = finI[p];
        if (tid == 0) loss += fabsf(bv - 1.0f);
        if (v0 == j) { t0 = true; m0 = FINF; }
        if (v1 == j) { t1 = true; m1 = FINF; }
        p ^= 1;
    }

    if (tid == 0) loss_out[c] = loss / (float)(NPT - 1);
}

__global__ void finalize_kernel(const float* __restrict__ loss, float* __restrict__ out) {
    if (threadIdx.x == 0 && blockIdx.x == 0) {
        float s = 0.0f;
        for (int c = 0; c < NCLS; ++c) s += loss[c];
        out[0] = s;
    }
}

extern "C" void kernel_launch(void* const* d_in, const int* in_sizes, int n_in,
                              void* d_out, int out_size, void* d_ws, size_t ws_size,
                              hipStream_t stream) {
    const float* x   = (const float*)d_in[0];
    float*       out = (float*)d_out;

    const size_t nv = (size_t)NCLS * NPT;
    const size_t nx = (size_t)NCLS * NPT * DIM;

    const size_t off_me   = 0;                                  // u64, 8-aligned
    const size_t off_sq   = off_me + nv * sizeof(u64);
    const size_t off_comp = off_sq + nv * sizeof(float);
    const size_t off_loss = off_comp + nv * sizeof(u32);
    const size_t off_done = off_loss + NCLS * sizeof(float);
    const size_t off_xh   = off_done + NCLS * sizeof(u32);
    const size_t need     = off_xh + nx * sizeof(u16);

    if (ws_size >= need) {
        u64*   minEdge = (u64*)((char*)d_ws + off_me);
        float* sq      = (float*)((char*)d_ws + off_sq);
        u32*   comp    = (u32*)((char*)d_ws + off_comp);
        float* lossAcc = (float*)((char*)d_ws + off_loss);
        u32*   done    = (u32*)((char*)d_ws + off_done);
        u16*   xh      = (u16*)((char*)d_ws + off_xh);

        convinit_kernel<<<(NCLS * NPT) / 4, 256, 0, stream>>>(x, xh, sq, comp,
                                                              minEdge, lossAcc, done);
        for (int r = 0; r < 11; ++r) {
            scan2h_kernel<<<dim3(4, NPT / 128, NCLS), 256, 0, stream>>>(
                xh, sq, comp, minEdge, done);
            merge_kernel<<<NCLS, 256, 0, stream>>>(comp, minEdge, lossAcc, done);
        }
        final2_kernel<<<1, 64, 0, stream>>>(lossAcc, out);
    } else {
        float* loss = (float*)d_ws;
        prim_onfly_kernel<<<NCLS, 1024, 0, stream>>>(x, loss);
        finalize_kernel<<<1, 64, 0, stream>>>(loss, out);
    }
}